// Round 3
// baseline (339.267 us; speedup 1.0000x reference)
//
#include <hip/hip_runtime.h>

// 8x8 block DCT: C = A * B * A^T per non-overlapping block.
// R3: LDS staging cut 32 KiB -> 16 KiB (4 quarter-phases, one wave stages its
// 64 blocks per phase, all 256 threads drain with coalesced 4 KiB stores).
// Residency limiter moves from LDS (5 WG/CU) to block-size (8 WG/CU = 32
// waves/CU); grid 2048 = exactly 8 WG/CU co-resident. R2 was latency-bound:
// Occupancy 34%, VALUBusy 9%, BW 2.7 TB/s. Stores are non-temporal (streaming
// output; don't thrash L2/L3 against the L3-warm input).

using vf4 = __attribute__((ext_vector_type(4))) float;

__global__ __launch_bounds__(256, 8) void dct8x8_kernel(const float* __restrict__ x,
                                                        float* __restrict__ out) {
    constexpr float A[8][8] = {
        { 0.35355339059327373f,  0.35355339059327373f,  0.35355339059327373f,  0.35355339059327373f,
          0.35355339059327373f,  0.35355339059327373f,  0.35355339059327373f,  0.35355339059327373f},
        { 0.49039264020161522f,  0.41573480615127262f,  0.27778511650980114f,  0.09754516100806417f,
         -0.09754516100806417f, -0.27778511650980114f, -0.41573480615127262f, -0.49039264020161522f},
        { 0.46193976625564337f,  0.19134171618254492f, -0.19134171618254492f, -0.46193976625564337f,
         -0.46193976625564337f, -0.19134171618254492f,  0.19134171618254492f,  0.46193976625564337f},
        { 0.41573480615127262f, -0.09754516100806417f, -0.49039264020161522f, -0.27778511650980114f,
          0.27778511650980114f,  0.49039264020161522f,  0.09754516100806417f, -0.41573480615127262f},
        { 0.35355339059327373f, -0.35355339059327373f, -0.35355339059327373f,  0.35355339059327373f,
          0.35355339059327373f, -0.35355339059327373f, -0.35355339059327373f,  0.35355339059327373f},
        { 0.27778511650980114f, -0.49039264020161522f,  0.09754516100806417f,  0.41573480615127262f,
         -0.41573480615127262f, -0.09754516100806417f,  0.49039264020161522f, -0.27778511650980114f},
        { 0.19134171618254492f, -0.46193976625564337f,  0.46193976625564337f, -0.19134171618254492f,
         -0.19134171618254492f,  0.46193976625564337f, -0.46193976625564337f,  0.19134171618254492f},
        { 0.09754516100806417f, -0.27778511650980114f,  0.41573480615127262f, -0.49039264020161522f,
          0.49039264020161522f, -0.41573480615127262f,  0.27778511650980114f, -0.09754516100806417f},
    };

    __shared__ float4 lds4[1024];  // 16 KiB staging (one quarter-phase)

    const int tl = threadIdx.x;
    const int t  = blockIdx.x * 256 + tl;

    // t -> (image n, block-row bi, block-col bj); 128x128 blocks per image
    const int n  = t >> 14;
    const int rm = t & 16383;
    const int bi = rm >> 7;
    const int bj = rm & 127;

    const float* src = x + (((size_t)n << 20) + ((size_t)bi << 13) + ((size_t)bj << 3));

    // Load row j, fold into M = B * A^T row-by-row (row j of M needs only row
    // j of B): M[j][m] = sum_l B[j][l] * A[m][l]
    float M[8][8];
#pragma unroll
    for (int j = 0; j < 8; ++j) {
        const float4 lo = *reinterpret_cast<const float4*>(src + (size_t)j * 1024);
        const float4 hi = *reinterpret_cast<const float4*>(src + (size_t)j * 1024 + 4);
        const float b[8] = {lo.x, lo.y, lo.z, lo.w, hi.x, hi.y, hi.z, hi.w};
#pragma unroll
        for (int m = 0; m < 8; ++m) {
            float acc = b[0] * A[m][0];
#pragma unroll
            for (int l = 1; l < 8; ++l) acc = fmaf(b[l], A[m][l], acc);
            M[j][m] = acc;
        }
    }

    // Workgroup w owns blocks [w*256, w*256+256) -> output floats [w*16384, ...).
    float* outw = out + ((size_t)blockIdx.x << 14);

    const int wv = tl >> 6;   // wave id 0..3 (wave-uniform)
    const int tr = tl & 63;   // lane within wave

#pragma unroll
    for (int p = 0; p < 4; ++p) {
        if (wv == p) {
            // C = A * M, row by row, into swizzled LDS (f ^ ((f>>4)&15):
            // staging write and coalesced read both land <=2-way conflicts).
#pragma unroll
            for (int i = 0; i < 8; ++i) {
                float c[8];
#pragma unroll
                for (int m = 0; m < 8; ++m) {
                    float acc = A[i][0] * M[0][m];
#pragma unroll
                    for (int j = 1; j < 8; ++j) acc = fmaf(A[i][j], M[j][m], acc);
                    c[m] = acc;
                }
                const int f0 = tr * 16 + i * 2;   // logical float4 index, 0..1023
                const int f1 = f0 + 1;
                lds4[f0 ^ ((f0 >> 4) & 15)] = make_float4(c[0], c[1], c[2], c[3]);
                lds4[f1 ^ ((f1 >> 4) & 15)] = make_float4(c[4], c[5], c[6], c[7]);
            }
        }
        __syncthreads();
        // Drain: 1024 float4 = 16 KiB contiguous, 4 iters x 4 KiB/instruction.
        // Phase p's 64 blocks -> floats [w*16384 + p*4096, +4096).
        float4* dst4 = reinterpret_cast<float4*>(outw + p * 4096);
#pragma unroll
        for (int s = 0; s < 4; ++s) {
            const int f4 = s * 256 + tl;
            const float4 val = lds4[f4 ^ ((f4 >> 4) & 15)];
            vf4 v = {val.x, val.y, val.z, val.w};
            __builtin_nontemporal_store(v, reinterpret_cast<vf4*>(&dst4[f4]));
        }
        __syncthreads();  // protect LDS reuse by the next phase
    }
}

extern "C" void kernel_launch(void* const* d_in, const int* in_sizes, int n_in,
                              void* d_out, int out_size, void* d_ws, size_t ws_size,
                              hipStream_t stream) {
    const float* x = (const float*)d_in[0];
    float* out = (float*)d_out;

    const int nblocks = out_size / 64;        // 524288
    const int grid = nblocks / 256;           // 2048 workgroups, exact
    dct8x8_kernel<<<grid, 256, 0, stream>>>(x, out);
}